// Round 5
// baseline (869.393 us; speedup 1.0000x reference)
//
#include <hip/hip_runtime.h>

#define HID    64
#define TSTEPS 256
#define BATCH  2048

typedef float v2f __attribute__((ext_vector_type(2)));

// tanh(x) = 1 - 2/(exp2(2*log2(e)*x) + 1); exact at saturation
__device__ __forceinline__ float fast_tanh(float x) {
    float e = __builtin_amdgcn_exp2f(x * 2.8853900817779268f);
    float r = __builtin_amdgcn_rcpf(e + 1.0f);
    return fmaf(-2.0f, r, 1.0f);
}

// xor-exchange within 32-lane halves, imm pattern (BitMode: xor=M, and=0x1F)
template <int M>
__device__ __forceinline__ float swz(float v) {
    return __int_as_float(__builtin_amdgcn_ds_swizzle(
        __float_as_int(v), (M << 10) | 0x1F));
}
template <int M>
__device__ __forceinline__ v2f swz2(v2f v) {
    v2f r; r.x = swz<M>(v.x); r.y = swz<M>(v.y); return r;
}

// DPP exchanges (pure VALU): 0xB1 quad_perm = lane^1, 0x4E quad_perm = lane^2,
// 0x128 row_ror:8 = lane^8 (rotate-by-8 within a 16-lane row == xor 8)
template <int CTRL>
__device__ __forceinline__ float dppf(float x) {
    int xi = __float_as_int(x);
    return __int_as_float(__builtin_amdgcn_update_dpp(xi, xi, CTRL, 0xF, 0xF, false));
}
template <int CTRL>
__device__ __forceinline__ v2f dpp2(v2f v) {
    v2f r; r.x = dppf<CTRL>(v.x); r.y = dppf<CTRL>(v.y); return r;
}

__device__ __forceinline__ float bperm(int addr, float v) {
    return __int_as_float(__builtin_amdgcn_ds_bpermute(addr, __float_as_int(v)));
}

__global__ __launch_bounds__(256, 2) void hnn_rk4_kernel(
        const float* __restrict__ tarr,
        const float* __restrict__ x0,
        const float* __restrict__ W1,
        const float* __restrict__ b1,
        const float* __restrict__ W2,
        const float* __restrict__ b2,
        const float* __restrict__ W3,
        float* __restrict__ out)
{
    const int lane = threadIdx.x & 63;
    const int wid  = threadIdx.x >> 6;
    const int b    = blockIdx.x * 4 + wid;     // one wave per batch element

    // 8x8 lane grid: lane = 8*r + c; lane owns W2 rows r0..r0+7 x cols c0..c0+7.
    // The SAME block serves forward (reduce over c-lanes) and backward
    // (reduce over r-lanes) -> no transposed copy (halves weight registers).
    const int rr = lane >> 3,  cc = lane & 7;
    const int r0 = rr << 3,    c0 = cc << 3;

    const float dt  = tarr[1] - tarr[0];
    const float hdt = 0.5f * dt;
    const float sdt = dt * (1.0f / 6.0f);

    // per-unit params (unit index = lane)
    v2f   w1v = *(const v2f*)(W1 + 2 * lane);
    float b1i = b1[lane];
    float b2i = b2[lane];
    float w3i = W3[lane];

    // broadcast addresses
    int ba[8], br[8];
#pragma unroll
    for (int t = 0; t < 8; ++t) {
        ba[t] = (c0 + t) * 4;                  // h1 over col-group (forward)
        br[t] = (r0 + t) * 4;                  // g2 over row-group (backward)
    }
    int a32 = (lane ^ 32) * 4;
    // backward reduce leaves u[8c + rev3(r)] on lane (r,c); transpose bperm:
    // holder of u[8r+c] is lane 8*rev3(c) + r
    const int rv = ((cc & 1) << 2) | (cc & 2) | ((cc >> 2) & 1);
    int atr = (8 * rv + rr) * 4;

    // forward weight pairs over OUTPUT rows: wfT[t*4+m] = (W2[r0+2m][c0+t], W2[r0+2m+1][c0+t])
    v2f wfT[32];
#pragma unroll
    for (int t = 0; t < 8; ++t) {
#pragma unroll
        for (int m = 0; m < 4; ++m) {
            v2f f;
            f.x = W2[(r0 + 2 * m)     * HID + c0 + t];
            f.y = W2[(r0 + 2 * m + 1) * HID + c0 + t];
            wfT[t * 4 + m] = f;
        }
    }

    const bool s1b = lane & 1,  s2b = lane & 2,  s4b = lane & 4;
    const bool rb0 = lane & 8,  rb1 = lane & 16, rb2 = lane & 32;

    // forward reduce over the 8 col-lanes (bits 0..2), halving order (2,4,1):
    // lane (r,c) ends with the full sum for unit 8r+c.  (verified R4)
    auto reduce_pairs = [&](v2f P0, v2f P1, v2f P2, v2f P3) -> float {
        v2f kA0 = s2b ? P1 : P0,  sA0 = s2b ? P0 : P1;
        v2f kA1 = s2b ? P3 : P2,  sA1 = s2b ? P2 : P3;
        v2f g0 = kA0 + dpp2<0x4E>(sA0);
        v2f g1 = kA1 + dpp2<0x4E>(sA1);
        v2f kB = s4b ? g1 : g0,   sB = s4b ? g0 : g1;
        v2f h  = kB + swz2<4>(sB);
        v2f vf = h + dpp2<0xB1>(h);
        return s1b ? vf.y : vf.x;
    };

    float q = x0[2 * b + 0];
    float p = x0[2 * b + 1];

    if (lane == 0) {
        out[2 * b + 0] = q;
        out[2 * b + 1] = p;
    }

    auto dynamics = [&](float xq, float xp, float& kq, float& kp) {
        // layer 1 (own unit = lane)
        const float h1 = fast_tanh(fmaf(w1v.x, xq, fmaf(w1v.y, xp, b1i)));

        // broadcast h1 over col-group
        float hb[8];
#pragma unroll
        for (int t = 0; t < 8; ++t) hb[t] = bperm(ba[t], h1);

        // forward partial pairs
        v2f P0 = {0.f, 0.f}, P1 = {0.f, 0.f}, P2 = {0.f, 0.f}, P3 = {0.f, 0.f};
#pragma unroll
        for (int t = 0; t < 8; ++t) {
            v2f hh; hh.x = hb[t]; hh.y = hb[t];
            P0 = __builtin_elementwise_fma(wfT[t * 4 + 0], hh, P0);
            P1 = __builtin_elementwise_fma(wfT[t * 4 + 1], hh, P1);
            P2 = __builtin_elementwise_fma(wfT[t * 4 + 2], hh, P2);
            P3 = __builtin_elementwise_fma(wfT[t * 4 + 3], hh, P3);
        }
        const float pre2 = reduce_pairs(P0, P1, P2, P3) + b2i;
        const float h2   = fast_tanh(pre2);
        const float g2v  = w3i * fmaf(-h2, h2, 1.0f);

        // broadcast g2 over ROW-group; backward uses the SAME wfT block:
        // uP[t] = partial of u[8c+t] = sum_m (g2[r0+2m], g2[r0+2m+1]) . wfT[t*4+m]
        float gb[8];
#pragma unroll
        for (int t = 0; t < 8; ++t) gb[t] = bperm(br[t], g2v);
        v2f gp[4];
#pragma unroll
        for (int m = 0; m < 4; ++m) { gp[m].x = gb[2 * m]; gp[m].y = gb[2 * m + 1]; }

        float uP[8];
#pragma unroll
        for (int t = 0; t < 8; ++t) {
            v2f acc = gp[0] * wfT[t * 4 + 0];
            acc = __builtin_elementwise_fma(gp[1], wfT[t * 4 + 1], acc);
            acc = __builtin_elementwise_fma(gp[2], wfT[t * 4 + 2], acc);
            acc = __builtin_elementwise_fma(gp[3], wfT[t * 4 + 3], acc);
            uP[t] = acc.x + acc.y;
        }

        // reduce over the 8 row-lanes (lane bits 3,4,5), bit-reversed landing:
        // stage 1: value bit2 <-> lane bit3 (xor8 via DPP row_ror:8)
        float v4[4];
#pragma unroll
        for (int t = 0; t < 4; ++t) {
            float keep = rb0 ? uP[t + 4] : uP[t];
            float send = rb0 ? uP[t]     : uP[t + 4];
            v4[t] = keep + dppf<0x128>(send);
        }
        // stage 2: value bit1 <-> lane bit4 (xor16 via swizzle)
        float w2v[2];
#pragma unroll
        for (int k = 0; k < 2; ++k) {
            float keep = rb1 ? v4[k + 2] : v4[k];
            float send = rb1 ? v4[k]     : v4[k + 2];
            w2v[k] = keep + swz<16>(send);
        }
        // stage 3: value bit0 <-> lane bit5 (xor32 via bpermute)
        float keep3 = rb2 ? w2v[1] : w2v[0];
        float send3 = rb2 ? w2v[0] : w2v[1];
        float upre  = keep3 + bperm(a32, send3);
        // transpose: fetch u[own unit 8r+c]
        const float u  = bperm(atr, upre);
        const float g1 = u * fmaf(-h1, h1, 1.0f);

        // dHdx = W1^T g1 : full-wave butterfly on (dH/dq, dH/dp)
        v2f gv; gv.x = g1; gv.y = g1;
        v2f sv = w1v * gv;
        sv = sv + dpp2<0xB1>(sv);                // xor1  (DPP)
        sv = sv + dpp2<0x4E>(sv);                // xor2  (DPP)
        sv = sv + swz2<4>(sv);                   // xor4
        sv = sv + dpp2<0x128>(sv);               // xor8  (DPP row_ror:8)
        sv = sv + swz2<16>(sv);                  // xor16
        v2f sw; sw.x = bperm(a32, sv.x); sw.y = bperm(a32, sv.y);
        sv = sv + sw;                            // xor32
        kq = sv.y;      //  dH/dp
        kp = -sv.x;     // -dH/dq
    };

#pragma unroll 1
    for (int s = 0; s < TSTEPS - 1; ++s) {
        // Residence pin once per step: forces all weights + addresses to be in
        // architectural VGPRs here, so AGPR-parking buys the allocator nothing.
#pragma unroll
        for (int k = 0; k < 32; ++k) asm volatile("" : "+v"(wfT[k]));
#pragma unroll
        for (int t = 0; t < 8; ++t) asm volatile("" : "+v"(ba[t]), "+v"(br[t]));
        asm volatile("" : "+v"(a32), "+v"(atr));

        float kq1, kp1, kq2, kp2, kq3, kp3, kq4, kp4;
        dynamics(q, p, kq1, kp1);
        dynamics(fmaf(hdt, kq1, q), fmaf(hdt, kp1, p), kq2, kp2);
        dynamics(fmaf(hdt, kq2, q), fmaf(hdt, kp2, p), kq3, kp3);
        dynamics(fmaf(dt,  kq3, q), fmaf(dt,  kp3, p), kq4, kp4);
        q = fmaf(sdt, kq1 + 2.f * kq2 + 2.f * kq3 + kq4, q);
        p = fmaf(sdt, kp1 + 2.f * kp2 + 2.f * kp3 + kp4, p);
        if (lane == 0) {
            out[(s + 1) * (BATCH * 2) + 2 * b + 0] = q;
            out[(s + 1) * (BATCH * 2) + 2 * b + 1] = p;
        }
    }
}

extern "C" void kernel_launch(void* const* d_in, const int* in_sizes, int n_in,
                              void* d_out, int out_size, void* d_ws, size_t ws_size,
                              hipStream_t stream) {
    const float* t  = (const float*)d_in[0];
    const float* x0 = (const float*)d_in[1];
    const float* W1 = (const float*)d_in[2];
    const float* b1 = (const float*)d_in[3];
    const float* W2 = (const float*)d_in[4];
    const float* b2 = (const float*)d_in[5];
    const float* W3 = (const float*)d_in[6];
    // d_in[7] = b3: additive constant in H, cancels in dH/dx — unused.

    hnn_rk4_kernel<<<dim3(BATCH / 4), dim3(256), 0, stream>>>(
        t, x0, W1, b1, W2, b2, W3, (float*)d_out);
}

// Round 6
// 790.223 us; speedup vs baseline: 1.1002x; 1.1002x over previous
//
#include <hip/hip_runtime.h>

#define HID    64
#define TSTEPS 256
#define BATCH  2048

typedef float v2f __attribute__((ext_vector_type(2)));

// tanh(x) = 1 - 2/(exp2(2*log2(e)*x) + 1); exact at saturation
__device__ __forceinline__ float fast_tanh(float x) {
    float e = __builtin_amdgcn_exp2f(x * 2.8853900817779268f);
    float r = __builtin_amdgcn_rcpf(e + 1.0f);
    return fmaf(-2.0f, r, 1.0f);
}

// ds_swizzle xor-exchange within 32-lane halves (BitMode: xor=M, and=0x1F)
template <int M>
__device__ __forceinline__ float swz(float v) {
    return __int_as_float(__builtin_amdgcn_ds_swizzle(
        __float_as_int(v), (M << 10) | 0x1F));
}

// DPP move (compiler handles hazards). 0xB1 quad_perm=lane^1, 0x4E quad_perm=lane^2,
// 0x121/2/4/8 row_ror:1/2/4/8 (ror:8 within 16-lane row == lane^8 exactly)
template <int CTRL>
__device__ __forceinline__ float dppx(float x) {
    int xi = __float_as_int(x);
    return __int_as_float(__builtin_amdgcn_update_dpp(xi, xi, CTRL, 0xF, 0xF, false));
}

__device__ __forceinline__ float bperm(int addr, float v) {
    return __int_as_float(__builtin_amdgcn_ds_bpermute(addr, __float_as_int(v)));
}

// guaranteed packed f32 FMA: acc += w * hv  (hv = duplicated scalar pair)
__device__ __forceinline__ void pkfma(v2f& acc, v2f w, v2f hv) {
    asm("v_pk_fma_f32 %0, %1, %2, %0" : "+v"(acc) : "v"(w), "v"(hv));
}

// full 64-lane sum via DPP rotates + row broadcasts; result returned uniform (lane 63)
__device__ __forceinline__ float wave_sum(float v) {
    v += dppx<0x121>(v);                       // ror:1
    v += dppx<0x122>(v);                       // ror:2
    v += dppx<0x124>(v);                       // ror:4
    v += dppx<0x128>(v);                       // ror:8  -> row totals
    v += __int_as_float(__builtin_amdgcn_update_dpp(
            0, __float_as_int(v), 0x142, 0xA, 0xF, false));   // bcast15 -> rows 1,3
    v += __int_as_float(__builtin_amdgcn_update_dpp(
            0, __float_as_int(v), 0x143, 0xC, 0xF, false));   // bcast31 -> rows 2,3
    return __int_as_float(__builtin_amdgcn_readlane(__float_as_int(v), 63));
}

__device__ __forceinline__ int rev3(int x) {   // 3-bit reversal (involution)
    return ((x & 1) << 2) | (x & 2) | ((x >> 2) & 1);
}

__global__ __launch_bounds__(256, 1) void hnn_rk4_kernel(
        const float* __restrict__ tarr,
        const float* __restrict__ x0,
        const float* __restrict__ W1,
        const float* __restrict__ b1,
        const float* __restrict__ W2,
        const float* __restrict__ b2,
        const float* __restrict__ W3,
        float* __restrict__ out)
{
    const int lane = threadIdx.x & 63;
    const int wid  = threadIdx.x >> 6;
    const int b    = blockIdx.x * 4 + wid;     // one wave per batch element

    // 8x8 lane grid; lane (rr,cc) owns W2 rows r0..r0+7 x cols c0..c0+7 and
    // owns hidden unit uo = 8*rr + rev3(cc)  (rev3 makes the scatter-reduces
    // position-uniform: no cndmask keep/send selection anywhere).
    const int rr = lane >> 3, cc = lane & 7;
    const int pc = rev3(cc),  pr = rev3(rr);
    const int uo = 8 * rr + pc;

    const float dt  = tarr[1] - tarr[0];
    const float hdt = 0.5f * dt;
    const float sdt = dt * (1.0f / 6.0f);

    // per-own-unit params
    const float w1a = W1[2 * uo + 0];
    const float w1b = W1[2 * uo + 1];
    const float b1i = b1[uo];
    const float b2i = b2[uo];
    const float w3i = W3[uo];

    // broadcast addresses: owner of unit 8a+t is lane 8a + rev3(t)
    int ba[8], br[8];
#pragma unroll
    for (int t = 0; t < 8; ++t) {
        ba[t] = (8 * cc + rev3(t)) * 4;        // h1[8cc+t] for forward
        br[t] = (8 * rr + rev3(t)) * 4;        // g2[8rr+t] for backward
    }
    int a32 = (lane ^ 32) * 4;                 // xor32 exchange (backward reduce)
    int atr = (8 * cc + rr) * 4;               // holder of u[own unit]

    // forward weights, paired over output rows, positions pre-XORed by rev3(cc):
    //   wsF[t][m] = ( W2[8rr + ((2m)^pc)][8cc+t], W2[8rr + ((2m+1)^pc)][8cc+t] )
    // backward weights, paired over cols, positions pre-XORed by rev3(rr):
    //   wsB[o][u] = ( W2[8rr+o][8cc + ((2u)^pr)], W2[8rr+o][8cc + ((2u+1)^pr)] )
    v2f wsF[8][4], wsB[8][4];
#pragma unroll
    for (int t = 0; t < 8; ++t) {
#pragma unroll
        for (int m = 0; m < 4; ++m) {
            v2f f;
            f.x = W2[(8 * rr + ((2 * m)     ^ pc)) * HID + 8 * cc + t];
            f.y = W2[(8 * rr + ((2 * m + 1) ^ pc)) * HID + 8 * cc + t];
            wsF[t][m] = f;
            v2f g;
            g.x = W2[(8 * rr + t) * HID + 8 * cc + ((2 * m)     ^ pr)];
            g.y = W2[(8 * rr + t) * HID + 8 * cc + ((2 * m + 1) ^ pr)];
            wsB[t][m] = g;
        }
    }

    float q = x0[2 * b + 0];
    float p = x0[2 * b + 1];

    if (lane == 0) {
        out[2 * b + 0] = q;
        out[2 * b + 1] = p;
    }

    auto dynamics = [&](float xq, float xp, float& kq, float& kp) {
        // layer 1 (own unit)
        const float h1 = fast_tanh(fmaf(w1a, xq, fmaf(w1b, xp, b1i)));

        // ---- forward: pre2 = W2 h1 + b2 ----
        float hb[8];
#pragma unroll
        for (int t = 0; t < 8; ++t) hb[t] = bperm(ba[t], h1);

        v2f P0 = {0.f, 0.f}, P1 = {0.f, 0.f}, P2 = {0.f, 0.f}, P3 = {0.f, 0.f};
#pragma unroll
        for (int t = 0; t < 8; ++t) {
            v2f hv; hv.x = hb[t]; hv.y = hb[t];
            pkfma(P0, wsF[t][0], hv);
            pkfma(P1, wsF[t][1], hv);
            pkfma(P2, wsF[t][2], hv);
            pkfma(P3, wsF[t][3], hv);
        }
        // uniform scatter-reduce over cc bits (mask1->posbit2, mask2->bit1, mask4->bit0)
        P0.x += dppx<0xB1>(P2.x);  P0.y += dppx<0xB1>(P2.y);
        P1.x += dppx<0xB1>(P3.x);  P1.y += dppx<0xB1>(P3.y);
        P0.x += dppx<0x4E>(P1.x);  P0.y += dppx<0x4E>(P1.y);
        const float pre2 = P0.x + swz<4>(P0.y) + b2i;

        const float h2 = fast_tanh(pre2);
        const float g2 = w3i * fmaf(-h2, h2, 1.0f);

        // ---- backward: u = W2^T g2 ----
        float gb[8];
#pragma unroll
        for (int o = 0; o < 8; ++o) gb[o] = bperm(br[o], g2);

        v2f Q0 = {0.f, 0.f}, Q1 = {0.f, 0.f}, Q2 = {0.f, 0.f}, Q3 = {0.f, 0.f};
#pragma unroll
        for (int o = 0; o < 8; ++o) {
            v2f gv; gv.x = gb[o]; gv.y = gb[o];
            pkfma(Q0, wsB[o][0], gv);
            pkfma(Q1, wsB[o][1], gv);
            pkfma(Q2, wsB[o][2], gv);
            pkfma(Q3, wsB[o][3], gv);
        }
        // uniform scatter-reduce over rr bits (mask8->posbit2, mask16->bit1, mask32->bit0)
        Q0.x += dppx<0x128>(Q2.x);  Q0.y += dppx<0x128>(Q2.y);   // ror:8 == lane^8
        Q1.x += dppx<0x128>(Q3.x);  Q1.y += dppx<0x128>(Q3.y);
        Q0.x += swz<16>(Q1.x);      Q0.y += swz<16>(Q1.y);
        const float upre = Q0.x + bperm(a32, Q0.y);
        const float u    = bperm(atr, upre);                     // fetch own unit's u
        const float g1   = u * fmaf(-h1, h1, 1.0f);

        // ---- dHdx = W1^T g1 : full-wave sums, DS-free ----
        kq =  wave_sum(g1 * w1b);   //  dH/dp
        kp = -wave_sum(g1 * w1a);   // -dH/dq
    };

#pragma unroll 1
    for (int s = 0; s < TSTEPS - 1; ++s) {
        float kq1, kp1, kq2, kp2, kq3, kp3, kq4, kp4;
        dynamics(q, p, kq1, kp1);
        dynamics(fmaf(hdt, kq1, q), fmaf(hdt, kp1, p), kq2, kp2);
        dynamics(fmaf(hdt, kq2, q), fmaf(hdt, kp2, p), kq3, kp3);
        dynamics(fmaf(dt,  kq3, q), fmaf(dt,  kp3, p), kq4, kp4);
        q = fmaf(sdt, (kq1 + kq4) + 2.0f * (kq2 + kq3), q);
        p = fmaf(sdt, (kp1 + kp4) + 2.0f * (kp2 + kp3), p);
        if (lane == 0) {
            out[(s + 1) * (BATCH * 2) + 2 * b + 0] = q;
            out[(s + 1) * (BATCH * 2) + 2 * b + 1] = p;
        }
    }
}

extern "C" void kernel_launch(void* const* d_in, const int* in_sizes, int n_in,
                              void* d_out, int out_size, void* d_ws, size_t ws_size,
                              hipStream_t stream) {
    const float* t  = (const float*)d_in[0];
    const float* x0 = (const float*)d_in[1];
    const float* W1 = (const float*)d_in[2];
    const float* b1 = (const float*)d_in[3];
    const float* W2 = (const float*)d_in[4];
    const float* b2 = (const float*)d_in[5];
    const float* W3 = (const float*)d_in[6];
    // d_in[7] = b3: additive constant in H, cancels in dH/dx — unused.

    hnn_rk4_kernel<<<dim3(BATCH / 4), dim3(256), 0, stream>>>(
        t, x0, W1, b1, W2, b2, W3, (float*)d_out);
}

// Round 8
// 750.023 us; speedup vs baseline: 1.1592x; 1.0536x over previous
//
#include <hip/hip_runtime.h>

#define HID    64
#define TSTEPS 256
#define BATCH  2048

typedef float v2f __attribute__((ext_vector_type(2)));

// tanh(x) = 1 - 2/(exp2(2*log2(e)*x) + 1); exact at saturation
__device__ __forceinline__ float fast_tanh(float x) {
    float e = __builtin_amdgcn_exp2f(x * 2.8853900817779268f);
    float r = __builtin_amdgcn_rcpf(e + 1.0f);
    return fmaf(-2.0f, r, 1.0f);
}

// ds_swizzle xor-exchange within 32-lane halves (BitMode: xor=M, and=0x1F)
template <int M>
__device__ __forceinline__ float swz(float v) {
    return __int_as_float(__builtin_amdgcn_ds_swizzle(
        __float_as_int(v), (M << 10) | 0x1F));
}

// DPP move. 0xB1 quad_perm=lane^1, 0x4E quad_perm=lane^2, 0x128 row_ror:8 (==lane^8)
template <int CTRL>
__device__ __forceinline__ float dppx(float x) {
    int xi = __float_as_int(x);
    return __int_as_float(__builtin_amdgcn_update_dpp(xi, xi, CTRL, 0xF, 0xF, false));
}

__device__ __forceinline__ float bperm(int addr, float v) {
    return __int_as_float(__builtin_amdgcn_ds_bpermute(addr, __float_as_int(v)));
}

// packed f32 FMA (VOP3P needs 64-bit pair operands — R7 errata: no scalar src)
__device__ __forceinline__ void pkfma(v2f& acc, v2f w, v2f hv) {
    asm("v_pk_fma_f32 %0, %1, %2, %0" : "+v"(acc) : "v"(w), "v"(hv));
}

// full 64-lane sum via DPP rotates + row broadcasts; uniform result (lane 63)
__device__ __forceinline__ float wave_sum(float v) {
    v += dppx<0x121>(v);                       // ror:1
    v += dppx<0x122>(v);                       // ror:2
    v += dppx<0x124>(v);                       // ror:4
    v += dppx<0x128>(v);                       // ror:8  -> 16-row totals
    v += __int_as_float(__builtin_amdgcn_update_dpp(
            0, __float_as_int(v), 0x142, 0xA, 0xF, false));   // bcast15
    v += __int_as_float(__builtin_amdgcn_update_dpp(
            0, __float_as_int(v), 0x143, 0xC, 0xF, false));   // bcast31
    return __int_as_float(__builtin_amdgcn_readlane(__float_as_int(v), 63));
}

__device__ __forceinline__ int rev3(int x) {   // 3-bit reversal (involution)
    return ((x & 1) << 2) | (x & 2) | ((x >> 2) & 1);
}

__global__ __launch_bounds__(256) __attribute__((amdgpu_waves_per_eu(2, 2)))
void hnn_rk4_kernel(
        const float* __restrict__ tarr,
        const float* __restrict__ x0,
        const float* __restrict__ W1,
        const float* __restrict__ b1,
        const float* __restrict__ W2,
        const float* __restrict__ b2,
        const float* __restrict__ W3,
        float* __restrict__ out)
{
    const int lane = threadIdx.x & 63;
    const int wid  = threadIdx.x >> 6;
    const int b    = blockIdx.x * 4 + wid;     // one wave per batch element

    // 8x8 lane grid; lane (rr,cc) owns W2 rows 8rr..+7 x cols 8cc..+7 and
    // hidden unit uo = 8rr + rev3(cc) (rev3 -> position-uniform scatter-reduces).
    const int rr = lane >> 3, cc = lane & 7;
    const int pc = rev3(cc),  pr = rev3(rr);
    const int uo = 8 * rr + pc;
    // After the backward reduce this lane holds u[vu], vu = 8cc + pr (stays here).
    const int vu = 8 * cc + pr;

    const float dt  = tarr[1] - tarr[0];
    const float hdt = 0.5f * dt;
    const float sdt = dt * (1.0f / 6.0f);

    // per-own-unit params
    const float w1a = W1[2 * uo + 0];
    const float w1b = W1[2 * uo + 1];
    const float b1i = b1[uo];
    const float b2i = b2[uo];
    const float w3i = W3[uo];
    // W1 pair of the HELD unit vu (landing-agnostic dHdx wave-sum)
    const float w1va = W1[2 * vu + 0];
    const float w1vb = W1[2 * vu + 1];

    // broadcast addresses: owner of unit 8a+t is lane 8a + rev3(t)
    int ba[8], br[8];
#pragma unroll
    for (int t = 0; t < 8; ++t) {
        ba[t] = (8 * cc + rev3(t)) * 4;        // h1[8cc+t] for forward
        br[t] = (8 * rr + rev3(t)) * 4;        // g2[8rr+t] for backward
    }
    int a32 = (lane ^ 32) * 4;                 // xor32 exchange (backward reduce)
    int ath = (8 * cc + rr) * 4;               // owner lane of h1[vu]

    // forward weights, paired over output rows, positions pre-XORed by rev3(cc):
    //   wsF[t][m] = ( W2[8rr + ((2m)^pc)][8cc+t], W2[8rr + ((2m+1)^pc)][8cc+t] )
    // backward weights, paired over cols, positions pre-XORed by rev3(rr):
    //   wsB[o][m] = ( W2[8rr+o][8cc + ((2m)^pr)], W2[8rr+o][8cc + ((2m+1)^pr)] )
    v2f wsF[8][4], wsB[8][4];
#pragma unroll
    for (int t = 0; t < 8; ++t) {
#pragma unroll
        for (int m = 0; m < 4; ++m) {
            v2f f;
            f.x = W2[(8 * rr + ((2 * m)     ^ pc)) * HID + 8 * cc + t];
            f.y = W2[(8 * rr + ((2 * m + 1) ^ pc)) * HID + 8 * cc + t];
            wsF[t][m] = f;
            v2f g;
            g.x = W2[(8 * rr + t) * HID + 8 * cc + ((2 * m)     ^ pr)];
            g.y = W2[(8 * rr + t) * HID + 8 * cc + ((2 * m + 1) ^ pr)];
            wsB[t][m] = g;
        }
    }
    // setup-only identity pins: break rematerialization of the weight loads
#pragma unroll
    for (int t = 0; t < 8; ++t)
#pragma unroll
        for (int m = 0; m < 4; ++m)
            asm("" : "+v"(wsF[t][m]), "+v"(wsB[t][m]));

    float q = x0[2 * b + 0];
    float p = x0[2 * b + 1];

    if (lane == 0) {
        out[2 * b + 0] = q;
        out[2 * b + 1] = p;
    }

    auto dynamics = [&](float xq, float xp, float& kq, float& kp) {
        // layer 1 (own unit)
        const float h1 = fast_tanh(fmaf(w1a, xq, fmaf(w1b, xp, b1i)));

        // ---- forward: pre2 = W2 h1 + b2 ----
        float hb[8];
#pragma unroll
        for (int t = 0; t < 8; ++t) hb[t] = bperm(ba[t], h1);
        // prefetch h1 of the held unit vu (same DS batch, latency shared)
        const float h1v = bperm(ath, h1);

        v2f P0 = {0.f, 0.f}, P1 = {0.f, 0.f}, P2 = {0.f, 0.f}, P3 = {0.f, 0.f};
#pragma unroll
        for (int t = 0; t < 8; ++t) {
            v2f hv; hv.x = hb[t]; hv.y = hb[t];
            pkfma(P0, wsF[t][0], hv);
            pkfma(P1, wsF[t][1], hv);
            pkfma(P2, wsF[t][2], hv);
            pkfma(P3, wsF[t][3], hv);
        }
        // uniform scatter-reduce over cc bits (lane^1 -> slot^4, ^2 -> ^2, ^4 -> ^1)
        P0.x += dppx<0xB1>(P2.x);  P0.y += dppx<0xB1>(P2.y);
        P1.x += dppx<0xB1>(P3.x);  P1.y += dppx<0xB1>(P3.y);
        P0.x += dppx<0x4E>(P1.x);  P0.y += dppx<0x4E>(P1.y);
        const float pre2 = P0.x + swz<4>(P0.y) + b2i;

        const float h2 = fast_tanh(pre2);
        const float g2 = w3i * fmaf(-h2, h2, 1.0f);

        // ---- backward: u = W2^T g2 ----
        float gb[8];
#pragma unroll
        for (int o = 0; o < 8; ++o) gb[o] = bperm(br[o], g2);

        v2f Q0 = {0.f, 0.f}, Q1 = {0.f, 0.f}, Q2 = {0.f, 0.f}, Q3 = {0.f, 0.f};
#pragma unroll
        for (int o = 0; o < 8; ++o) {
            v2f gv; gv.x = gb[o]; gv.y = gb[o];
            pkfma(Q0, wsB[o][0], gv);
            pkfma(Q1, wsB[o][1], gv);
            pkfma(Q2, wsB[o][2], gv);
            pkfma(Q3, wsB[o][3], gv);
        }
        // uniform scatter-reduce over rr bits (lane^8, ^16, ^32)
        Q0.x += dppx<0x128>(Q2.x);  Q0.y += dppx<0x128>(Q2.y);
        Q1.x += dppx<0x128>(Q3.x);  Q1.y += dppx<0x128>(Q3.y);
        Q0.x += swz<16>(Q1.x);      Q0.y += swz<16>(Q1.y);
        const float uv = Q0.x + bperm(a32, Q0.y);     // = u[vu], stays on this lane

        // dH/dx contribution of unit vu; wave_sum is landing-agnostic
        const float g1v = uv * fmaf(-h1v, h1v, 1.0f);

        kq =  wave_sum(g1v * w1vb);   //  dH/dp
        kp = -wave_sum(g1v * w1va);   // -dH/dq
    };

#pragma unroll 1
    for (int s = 0; s < TSTEPS - 1; ++s) {
        float kq1, kp1, kq2, kp2, kq3, kp3, kq4, kp4;
        dynamics(q, p, kq1, kp1);
        dynamics(fmaf(hdt, kq1, q), fmaf(hdt, kp1, p), kq2, kp2);
        dynamics(fmaf(hdt, kq2, q), fmaf(hdt, kp2, p), kq3, kp3);
        dynamics(fmaf(dt,  kq3, q), fmaf(dt,  kp3, p), kq4, kp4);
        q = fmaf(sdt, (kq1 + kq4) + 2.0f * (kq2 + kq3), q);
        p = fmaf(sdt, (kp1 + kp4) + 2.0f * (kp2 + kp3), p);
        if (lane == 0) {
            out[(s + 1) * (BATCH * 2) + 2 * b + 0] = q;
            out[(s + 1) * (BATCH * 2) + 2 * b + 1] = p;
        }
    }
}

extern "C" void kernel_launch(void* const* d_in, const int* in_sizes, int n_in,
                              void* d_out, int out_size, void* d_ws, size_t ws_size,
                              hipStream_t stream) {
    const float* t  = (const float*)d_in[0];
    const float* x0 = (const float*)d_in[1];
    const float* W1 = (const float*)d_in[2];
    const float* b1 = (const float*)d_in[3];
    const float* W2 = (const float*)d_in[4];
    const float* b2 = (const float*)d_in[5];
    const float* W3 = (const float*)d_in[6];
    // d_in[7] = b3: additive constant in H, cancels in dH/dx — unused.

    hnn_rk4_kernel<<<dim3(BATCH / 4), dim3(256), 0, stream>>>(
        t, x0, W1, b1, W2, b2, W3, (float*)d_out);
}